// Round 4
// baseline (1209.572 us; speedup 1.0000x reference)
//
#include <hip/hip_runtime.h>

// NonLinearSAGE: only nodes i % 3 == 0 reach the output -> aggregate only
// edges with dst % 3 == 0 into compact agg[dst/3] (1M floats).
//
// R4: ILP experiment. R2/R3 showed ~18-27 outstanding reqs/CU (Little's law
// at 600-900cyc latency) -> suspect per-wave ILP-bound, not atomic-rate-bound.
// 8 edges/thread, gathers hoisted ahead of atomics, VGPR kept <=64 so we hold
// 8 waves/SIMD. Single agg copy, device-scope atomics (R3 priv was neutral).

static constexpr int kEdges = 48000000;
static constexpr int kOut   = 1000000;   // kNodes / 3

typedef int v4i __attribute__((ext_vector_type(4)));

__global__ __launch_bounds__(256) void edge_scatter(
    const int* __restrict__ ei,
    const float* __restrict__ x,
    float* __restrict__ agg)
{
    const int tid  = blockIdx.x * blockDim.x + threadIdx.x;
    const long long base = (long long)tid * 8;      // 8 edges per thread
    if (base >= kEdges) return;                     // kEdges % 8 == 0

    // Edge stream: non-temporal (no reuse); x gathers stay cached (16x reuse).
    const v4i s01 = __builtin_nontemporal_load((const v4i*)(ei + base));
    const v4i s23 = __builtin_nontemporal_load((const v4i*)(ei + base + 4));
    const v4i d01 = __builtin_nontemporal_load((const v4i*)(ei + kEdges + base));
    const v4i d23 = __builtin_nontemporal_load((const v4i*)(ei + kEdges + base + 4));

    const int ss[8] = {s01.x, s01.y, s01.z, s01.w, s23.x, s23.y, s23.z, s23.w};
    const int dd[8] = {d01.x, d01.y, d01.z, d01.w, d23.x, d23.y, d23.z, d23.w};

    unsigned qi[8];
    bool     qq[8];
#pragma unroll
    for (int k = 0; k < 8; ++k) {
        const unsigned d = (unsigned)dd[k];
        const unsigned q = d / 3u;          // magic-multiply
        qi[k] = q;
        qq[k] = (q * 3u == d);
    }

    // All gathers issued before any atomic -> up to 8 independent loads in
    // flight per thread (vs ~1.3 in R2/R3).
    float vv[8];
#pragma unroll
    for (int k = 0; k < 8; ++k)
        if (qq[k]) vv[k] = x[ss[k]];

#pragma unroll
    for (int k = 0; k < 8; ++k)
        if (qq[k]) atomicAdd(agg + qi[k], vv[k]);
}

__global__ __launch_bounds__(256) void finalize(
    const float* __restrict__ agg,
    const float* __restrict__ x,
    const float* __restrict__ Wl,
    const float* __restrict__ Wr,
    const float* __restrict__ W1,
    const float* __restrict__ b1,
    const float* __restrict__ W2,
    const float* __restrict__ b2,
    float* __restrict__ out)
{
    const int j = blockIdx.x * blockDim.x + threadIdx.x;
    if (j >= kOut) return;

    const float h = agg[j] * Wl[0] + x[3 * j] * Wr[0];
    const float t0 = fmaxf(h * W1[0] + b1[0], 0.0f);
    const float t1 = fmaxf(h * W1[1] + b1[1], 0.0f);
    out[j] = t0 * W2[0] + t1 * W2[1] + b2[0];
}

extern "C" void kernel_launch(void* const* d_in, const int* in_sizes, int n_in,
                              void* d_out, int out_size, void* d_ws, size_t ws_size,
                              hipStream_t stream)
{
    const float* x  = (const float*)d_in[0];
    const int*   ei = (const int*)d_in[1];
    const float* Wl = (const float*)d_in[2];
    const float* Wr = (const float*)d_in[3];
    const float* W1 = (const float*)d_in[4];
    const float* b1 = (const float*)d_in[5];
    const float* W2 = (const float*)d_in[6];
    const float* b2 = (const float*)d_in[7];
    float* out = (float*)d_out;

    float* agg = (float*)d_ws;   // 4 MB, poisoned each call -> zero it
    hipMemsetAsync(agg, 0, kOut * sizeof(float), stream);

    const int nThreads = kEdges / 8;                       // 6M threads
    const int nBlocks  = (nThreads + 255) / 256;           // 23438
    edge_scatter<<<nBlocks, 256, 0, stream>>>(ei, x, agg);

    finalize<<<(kOut + 255) / 256, 256, 0, stream>>>(agg, x, Wl, Wr, W1, b1, W2, b2, out);
}